// Round 6
// baseline (22.057 us; speedup 1.0000x reference)
//
#include <hip/hip_runtime.h>

// Problem constants (from reference setup_inputs)
#define B_  4
#define H_  64
#define W_  64
#define C_  16
#define F_  32

#define NWE (8 * 9 * F_)   // 2304 weight float4 entries (36864 B LDS)

// Block = one output row (b, i): 512 threads = 8 waves, wave = 8-pixel strip.
// Lane = (ps 0/1, f 0..31); each lane computes 4 pixels (it) x 2 channels x 4 rotations.
// Weights: LDS (DS pipe). x: global->L1 (VMEM pipe, 12.7 KB/block working set).
// All 4 P4 rotations from one patch via compile-time permutation (max is
// permutation-invariant; verified rounds 2-5).
__global__ __launch_bounds__(512) void mtp_main(const float* __restrict__ x,
                                                const float* __restrict__ kern,
                                                const float* __restrict__ tker,
                                                float* __restrict__ out) {
    __shared__ float4 wlds[NWE];

    const int tid  = threadIdx.x;
    const int bidx = blockIdx.x;                 // b*64 + i
    const int i    = bidx & 63;
    const int b    = bidx >> 6;

    // ---- stage weights: [cc(8)][q(9)][f(32)] float4 = (t_c0, t_c1, k_c0, k_c1)
    #pragma unroll
    for (int e0 = 0; e0 < 5; ++e0) {
        int e = e0 * 512 + tid;
        if (e < NWE) {
            int f  = e & 31;
            int t  = e >> 5;
            int q  = t % 9;
            int cc = t / 9;
            int s0 = (q * C_ + cc * 2 + 0) * F_ + f;
            int s1 = (q * C_ + cc * 2 + 1) * F_ + f;
            wlds[e] = make_float4(tker[s0], tker[s1], kern[s0], kern[s1]);
        }
    }
    __syncthreads();

    const int lane = tid & 63;
    const int f    = lane & 31;
    const int ps   = lane >> 5;
    const int w    = tid >> 6;                   // wave 0..7
    const int jb   = w << 3;                     // 8-pixel strip base
    const int col0 = jb + ps - 1;                // leftmost halo col (may be -1)

    const bool okL = (col0 >= 0);                // false only for w=0, ps=0
    const bool okR = (col0 + 8 <= 63);           // false only for w=7, ps=1
    const bool ok0 = (i > 0);
    const bool ok2 = (i < 63);
    const int colL = okL ? col0 : 0;
    const int colR = okR ? col0 + 8 : 63;

    const float* rowp0 = x + ((b * H_ + (ok0 ? i - 1 : 0)) * W_) * C_;
    const float* rowp1 = x + ((b * H_ + i) * W_) * C_;
    const float* rowp2 = x + ((b * H_ + (ok2 ? i + 1 : 0)) * W_) * C_;

    float acc[4][4];
    #pragma unroll
    for (int r = 0; r < 4; ++r)
        #pragma unroll
        for (int it = 0; it < 4; ++it) acc[r][it] = 0.f;

    #pragma unroll 1
    for (int cc = 0; cc < 8; ++cc) {
        // weight batch: 9 ds_read_b128, lanes 0-31 consecutive 16B; ps-half broadcast
        float4 wq[9];
        #pragma unroll
        for (int q = 0; q < 9; ++q)
            wq[q] = wlds[(cc * 9 + q) * F_ + f];

        // x halo batch: 3 rows x 9 cols float2 via global (L1-resident).
        // Cols col0+1 .. col0+7 are always in-range; h=0 / h=8 use clamped bases.
        float2 xh[3][9];
        const float* rp[3] = { rowp0, rowp1, rowp2 };
        #pragma unroll
        for (int dr = 0; dr < 3; ++dr) {
            const float* rb = rp[dr];
            const float* bm = rb + (col0 + 1) * C_ + cc * 2;
            xh[dr][0] = *reinterpret_cast<const float2*>(rb + colL * C_ + cc * 2);
            #pragma unroll
            for (int h = 1; h <= 7; ++h)
                xh[dr][h] = *reinterpret_cast<const float2*>(bm + (h - 1) * C_);
            xh[dr][8] = *reinterpret_cast<const float2*>(rb + colR * C_ + cc * 2);
        }
        const float2 z2 = make_float2(0.f, 0.f);
        if (!okL) { xh[0][0] = z2; xh[1][0] = z2; xh[2][0] = z2; }   // divergent: cndmask
        if (!okR) { xh[0][8] = z2; xh[1][8] = z2; xh[2][8] = z2; }
        if (!ok0) {                                                   // uniform branch
            #pragma unroll
            for (int h = 0; h < 9; ++h) xh[0][h] = z2;
        }
        if (!ok2) {
            #pragma unroll
            for (int h = 0; h < 9; ++h) xh[2][h] = z2;
        }

        #pragma unroll
        for (int it = 0; it < 4; ++it) {
            #pragma unroll
            for (int r = 0; r < 4; ++r) {
                float z0[9], z1[9];
                #pragma unroll
                for (int q = 0; q < 9; ++q) {
                    const int a = q / 3, bq = q % 3;
                    int di, dj;
                    switch (r) {   // x position = rot_r^{-1}(weight position q)
                        case 0:  di = a;      dj = bq;     break;
                        case 1:  di = 2 - bq; dj = a;      break;
                        case 2:  di = 2 - a;  dj = 2 - bq; break;
                        default: di = bq;     dj = 2 - a;  break;
                    }
                    const float2 xv = xh[di][it * 2 + dj];
                    z0[q] = fmaf(xv.x, wq[q].x, wq[q].z);
                    z1[q] = fmaf(xv.y, wq[q].y, wq[q].w);
                }
                float m0 = fmaxf(fmaxf(fmaxf(z0[0], z0[1]), z0[2]),
                           fmaxf(fmaxf(fmaxf(z0[3], z0[4]), z0[5]),
                                 fmaxf(fmaxf(z0[6], z0[7]), z0[8])));
                float m1 = fmaxf(fmaxf(fmaxf(z1[0], z1[1]), z1[2]),
                           fmaxf(fmaxf(fmaxf(z1[3], z1[4]), z1[5]),
                                 fmaxf(fmaxf(z1[6], z1[7]), z1[8])));
                acc[r][it] += m0 + m1;
            }
        }
    }

    // out[b, r, i, jb+ps+it*2, f]; per (r,it) the wave stores 256B contiguous
    #pragma unroll
    for (int r = 0; r < 4; ++r) {
        float* op = out + ((((b * 4 + r) * H_ + i) * W_ + jb + ps) * F_ + f);
        #pragma unroll
        for (int it = 0; it < 4; ++it)
            op[it * 2 * F_] = acc[r][it];
    }
}

extern "C" void kernel_launch(void* const* d_in, const int* in_sizes, int n_in,
                              void* d_out, int out_size, void* d_ws, size_t ws_size,
                              hipStream_t stream) {
    const float* x    = (const float*)d_in[0];
    const float* kern = (const float*)d_in[1];
    const float* tker = (const float*)d_in[2];
    float* out = (float*)d_out;

    hipLaunchKernelGGL(mtp_main, dim3(B_ * H_), dim3(512), 0, stream,
                       x, kern, tker, out);
}